// Round 1
// baseline (698.822 us; speedup 1.0000x reference)
//
#include <hip/hip_runtime.h>
#include <cmath>
#include <cstdint>

namespace {
constexpr int      kL  = 16;
constexpr uint32_t kT  = 1u << 19;       // 524288 entries per level
constexpr int      kN  = 524288;         // points
constexpr uint32_t PI1 = 1u;
constexpr uint32_t PI2 = 2654435761u;    // wraps identically to int32 semantics
constexpr uint32_t PI3 = 805459861u;

struct Scales { float s[kL]; };
} // namespace

// One thread per point. Loops over 16 levels; 8 float2 gathers per level.
__global__ __launch_bounds__(256) void hashenc_kernel(
    const float* __restrict__ x,       // (N, 3)
    const float2* __restrict__ tab,    // (L, T) of float2  (i.e. (L,T,F=2))
    float2* __restrict__ out,          // (N, L) of float2  (i.e. (N, L*F))
    Scales sc)
{
  const int p = blockIdx.x * 256 + threadIdx.x;   // N % 256 == 0, no guard needed
  const float x0 = x[3 * p + 0];
  const float x1 = x[3 * p + 1];
  const float x2 = x[3 * p + 2];
  float2* op = out + (size_t)p * kL;

#pragma unroll 4
  for (int l = 0; l < kL; ++l) {
    const float s  = sc.s[l];
    const float p0 = x0 * s, p1 = x1 * s, p2 = x2 * s;
    const float f0 = floorf(p0), f1 = floorf(p1), f2 = floorf(p2);
    const float r0 = p0 - f0, r1 = p1 - f1, r2 = p2 - f2;
    const uint32_t c0 = (uint32_t)(int)f0;
    const uint32_t c1 = (uint32_t)(int)f1;
    const uint32_t c2 = (uint32_t)(int)f2;

    // Per-axis hash components; corner (ox,oy,oz) -> hx[ox]^hy[oy]^hz[oz]
    uint32_t hx[2], hy[2], hz[2];
    hx[0] = c0 * PI1;  hx[1] = hx[0] + PI1;
    hy[0] = c1 * PI2;  hy[1] = hy[0] + PI2;
    hz[0] = c2 * PI3;  hz[1] = hz[0] + PI3;

    float wx[2], wy[2], wz[2];
    wx[0] = 1.0f - r0; wx[1] = r0;
    wy[0] = 1.0f - r1; wy[1] = r1;
    wz[0] = 1.0f - r2; wz[1] = r2;

    const float2* tl = tab + (size_t)l * kT;
    float a0 = 0.0f, a1 = 0.0f;
#pragma unroll
    for (int ox = 0; ox < 2; ++ox)
#pragma unroll
      for (int oy = 0; oy < 2; ++oy)
#pragma unroll
        for (int oz = 0; oz < 2; ++oz) {
          const uint32_t idx = (hx[ox] ^ hy[oy] ^ hz[oz]) & (kT - 1u);
          const float2 g = tl[idx];
          const float  w = (wx[ox] * wy[oy]) * wz[oz];
          a0 += w * g.x;
          a1 += w * g.y;
        }
    op[l] = make_float2(a0, a1);
  }
}

extern "C" void kernel_launch(void* const* d_in, const int* in_sizes, int n_in,
                              void* d_out, int out_size, void* d_ws, size_t ws_size,
                              hipStream_t stream) {
  const float*  x   = (const float*)d_in[0];
  const float2* tab = (const float2*)d_in[1];
  float2*       out = (float2*)d_out;

  // Replicate reference n_levels in f32 on the HOST (glibc correctly-rounded
  // expf/logf/powf; analysis: n_levels[15] lands at 4095 because
  // f32(b)^15 = 255.99990 < 256). Passed by value to the kernel.
  Scales sc;
  const float b = expf(logf(256.0f) / 15.0f);
  for (int l = 0; l < kL; ++l)
    sc.s[l] = floorf(16.0f * powf(b, (float)l));

  hipLaunchKernelGGL(hashenc_kernel, dim3(kN / 256), dim3(256), 0, stream,
                     x, tab, out, sc);
}

// Round 2
// 445.199 us; speedup vs baseline: 1.5697x; 1.5697x over previous
//
#include <hip/hip_runtime.h>
#include <cmath>
#include <cstdint>

namespace {
constexpr int      kL  = 16;
constexpr uint32_t kT  = 1u << 19;       // 524288 entries per level
constexpr int      kN  = 524288;         // points
constexpr uint32_t PI1 = 1u;
constexpr uint32_t PI2 = 2654435761u;    // wraps identically to int32 semantics
constexpr uint32_t PI3 = 805459861u;

struct Scales { float s[kL]; };
} // namespace

// One thread per point, all 16 levels, but the LEVEL LOOP IS ROTATED per XCD
// (blockIdx % 8 == XCD, measured round-robin): XCD k starts at level 2k, so at
// any instant each XCD's ~32 CUs gather from ~1 level table (4 MB) == its L2
// capacity, instead of 16 tables (67 MB) thrashing it.
// Results accumulate in registers (statically indexed) and are written as 8
// contiguous float4 stores at the end for full-cacheline writebacks.
__global__ __launch_bounds__(256) void hashenc_kernel(
    const float* __restrict__ x,       // (N, 3)
    const float2* __restrict__ tab,    // (L, T) of float2
    float2* __restrict__ out,          // (N, L) of float2
    Scales sc)
{
  const int p = blockIdx.x * 256 + threadIdx.x;   // N % 256 == 0
  const int lstart = (blockIdx.x & 7) * 2;        // even rotation per XCD
  const float x0 = x[3 * p + 0];
  const float x1 = x[3 * p + 1];
  const float x2 = x[3 * p + 2];

  float2 acc[kL];                                  // static indexing only

#pragma unroll
  for (int i = 0; i < kL; ++i) {
    const int l = (lstart + i) & (kL - 1);         // wave-uniform rotated level
    const float s  = sc.s[l];
    const float p0 = x0 * s, p1 = x1 * s, p2 = x2 * s;
    const float f0 = floorf(p0), f1 = floorf(p1), f2 = floorf(p2);
    const float r0 = p0 - f0, r1 = p1 - f1, r2 = p2 - f2;
    const uint32_t c0 = (uint32_t)(int)f0;
    const uint32_t c1 = (uint32_t)(int)f1;
    const uint32_t c2 = (uint32_t)(int)f2;

    uint32_t hx[2], hy[2], hz[2];
    hx[0] = c0 * PI1;  hx[1] = hx[0] + PI1;
    hy[0] = c1 * PI2;  hy[1] = hy[0] + PI2;
    hz[0] = c2 * PI3;  hz[1] = hz[0] + PI3;

    float wx[2], wy[2], wz[2];
    wx[0] = 1.0f - r0; wx[1] = r0;
    wy[0] = 1.0f - r1; wy[1] = r1;
    wz[0] = 1.0f - r2; wz[1] = r2;

    const float2* tl = tab + (size_t)l * kT;
    float a0 = 0.0f, a1 = 0.0f;
#pragma unroll
    for (int ox = 0; ox < 2; ++ox)
#pragma unroll
      for (int oy = 0; oy < 2; ++oy)
#pragma unroll
        for (int oz = 0; oz < 2; ++oz) {
          const uint32_t idx = (hx[ox] ^ hy[oy] ^ hz[oz]) & (kT - 1u);
          const float2 g = tl[idx];
          const float  w = (wx[ox] * wy[oy]) * wz[oz];
          a0 += w * g.x;
          a1 += w * g.y;
        }
    acc[i] = make_float2(a0, a1);
  }

  // Write-back: pairs (i, i+1) map to levels (l, l+1) with no mod-16 wrap
  // inside a pair (lstart even), so each pair is a contiguous float4.
  float4* op4 = (float4*)(out + (size_t)p * kL);
#pragma unroll
  for (int i = 0; i < kL; i += 2) {
    const int l = (lstart + i) & (kL - 1);
    op4[l >> 1] = make_float4(acc[i].x, acc[i].y, acc[i + 1].x, acc[i + 1].y);
  }
}

extern "C" void kernel_launch(void* const* d_in, const int* in_sizes, int n_in,
                              void* d_out, int out_size, void* d_ws, size_t ws_size,
                              hipStream_t stream) {
  const float*  x   = (const float*)d_in[0];
  const float2* tab = (const float2*)d_in[1];
  float2*       out = (float2*)d_out;

  // Host-side f32 replication of reference n_levels (n[15] = 4095 — verified).
  Scales sc;
  const float b = expf(logf(256.0f) / 15.0f);
  for (int l = 0; l < kL; ++l)
    sc.s[l] = floorf(16.0f * powf(b, (float)l));

  hipLaunchKernelGGL(hashenc_kernel, dim3(kN / 256), dim3(256), 0, stream,
                     x, tab, out, sc);
}

// Round 4
// 415.578 us; speedup vs baseline: 1.6816x; 1.0713x over previous
//
#include <hip/hip_runtime.h>
#include <cmath>
#include <cstdint>

namespace {
constexpr int      kL  = 16;
constexpr uint32_t kT  = 1u << 19;       // 524288 entries per level
constexpr int      kN  = 524288;         // points
constexpr int      kChunks = kN / 256;   // 2048 point-chunks
constexpr uint32_t PI1 = 1u;
constexpr uint32_t PI2 = 2654435761u;
constexpr uint32_t PI3 = 805459861u;

typedef float f32x2 __attribute__((ext_vector_type(2)));
typedef float f32x4 __attribute__((ext_vector_type(4)));

struct Scales { float s[kL]; };
} // namespace

// ---------------- Phase 1: gather, level-major output ----------------
// Grid = 8 XCDs * 2 level-slots * 2048 chunks = 32768 blocks.
// b & 7  -> XCD c (measured round-robin mapping, m09)
// b >> 3 -> j in [0, 4096): j < 2048 -> level c, else level 15-c.
// Each XCD streams ALL points through level c first, then level 15-c:
// one 4-MB table resident per XCD L2 at any instant.
// ws written level-major (512 B contiguous per wave), non-temporal so the
// streaming store can't evict the table from L2.
__global__ __launch_bounds__(256) void hashenc_gather(
    const float* __restrict__ x,       // (N, 3)
    const f32x2* __restrict__ tab,     // (L, T)
    f32x2* __restrict__ ws,            // (L, N)
    Scales sc)
{
  const int c = blockIdx.x & 7;
  const int j = blockIdx.x >> 3;
  const int l = (j < kChunks) ? c : (15 - c);
  const int p = (j & (kChunks - 1)) * 256 + threadIdx.x;

  const float s  = sc.s[l];
  const float p0 = x[3 * p + 0] * s;
  const float p1 = x[3 * p + 1] * s;
  const float p2 = x[3 * p + 2] * s;
  const float f0 = floorf(p0), f1 = floorf(p1), f2 = floorf(p2);
  const float r0 = p0 - f0, r1 = p1 - f1, r2 = p2 - f2;

  uint32_t hx[2], hy[2], hz[2];
  hx[0] = (uint32_t)(int)f0 * PI1;  hx[1] = hx[0] + PI1;
  hy[0] = (uint32_t)(int)f1 * PI2;  hy[1] = hy[0] + PI2;
  hz[0] = (uint32_t)(int)f2 * PI3;  hz[1] = hz[0] + PI3;

  float wx[2] = {1.0f - r0, r0};
  float wy[2] = {1.0f - r1, r1};
  float wz[2] = {1.0f - r2, r2};

  const f32x2* tl = tab + (size_t)l * kT;
  float a0 = 0.0f, a1 = 0.0f;
#pragma unroll
  for (int ox = 0; ox < 2; ++ox)
#pragma unroll
    for (int oy = 0; oy < 2; ++oy)
#pragma unroll
      for (int oz = 0; oz < 2; ++oz) {
        const uint32_t idx = (hx[ox] ^ hy[oy] ^ hz[oz]) & (kT - 1u);
        const f32x2 g = tl[idx];
        const float w = (wx[ox] * wy[oy]) * wz[oz];
        a0 += w * g.x;
        a1 += w * g.y;
      }
  f32x2 r; r.x = a0; r.y = a1;
  __builtin_nontemporal_store(r, ws + (size_t)l * kN + p);
}

// ---------------- Phase 2: transpose (L,N,2) -> (N,L,2) ----------------
__global__ __launch_bounds__(256) void hashenc_transpose(
    const f32x2* __restrict__ ws,      // (L, N)
    f32x4* __restrict__ out)           // (N, L/2) f32x4 view of (N, L*F)
{
  const int p = blockIdx.x * 256 + threadIdx.x;
  f32x2 v[kL];
#pragma unroll
  for (int l = 0; l < kL; ++l)
    v[l] = __builtin_nontemporal_load(ws + (size_t)l * kN + p);
#pragma unroll
  for (int l = 0; l < kL; l += 2) {
    f32x4 o; o.x = v[l].x; o.y = v[l].y; o.z = v[l + 1].x; o.w = v[l + 1].y;
    __builtin_nontemporal_store(o, out + (size_t)p * (kL / 2) + (l >> 1));
  }
}

// ---------------- Fallback (R2 kernel): direct (N,L) writes ----------------
__global__ __launch_bounds__(256) void hashenc_direct(
    const float* __restrict__ x, const float2* __restrict__ tab,
    float2* __restrict__ out, Scales sc)
{
  const int p = blockIdx.x * 256 + threadIdx.x;
  const int lstart = (blockIdx.x & 7) * 2;
  const float x0 = x[3 * p + 0], x1 = x[3 * p + 1], x2 = x[3 * p + 2];
  float2 acc[kL];
#pragma unroll
  for (int i = 0; i < kL; ++i) {
    const int l = (lstart + i) & (kL - 1);
    const float s = sc.s[l];
    const float p0 = x0 * s, p1 = x1 * s, p2 = x2 * s;
    const float f0 = floorf(p0), f1 = floorf(p1), f2 = floorf(p2);
    const float r0 = p0 - f0, r1 = p1 - f1, r2 = p2 - f2;
    uint32_t hx[2], hy[2], hz[2];
    hx[0] = (uint32_t)(int)f0 * PI1; hx[1] = hx[0] + PI1;
    hy[0] = (uint32_t)(int)f1 * PI2; hy[1] = hy[0] + PI2;
    hz[0] = (uint32_t)(int)f2 * PI3; hz[1] = hz[0] + PI3;
    float wxa[2] = {1.0f - r0, r0}, wya[2] = {1.0f - r1, r1}, wza[2] = {1.0f - r2, r2};
    const float2* tl = tab + (size_t)l * kT;
    float a0 = 0.0f, a1 = 0.0f;
#pragma unroll
    for (int ox = 0; ox < 2; ++ox)
#pragma unroll
      for (int oy = 0; oy < 2; ++oy)
#pragma unroll
        for (int oz = 0; oz < 2; ++oz) {
          const uint32_t idx = (hx[ox] ^ hy[oy] ^ hz[oz]) & (kT - 1u);
          const float2 g = tl[idx];
          const float  w = (wxa[ox] * wya[oy]) * wza[oz];
          a0 += w * g.x; a1 += w * g.y;
        }
    acc[i] = make_float2(a0, a1);
  }
  float4* op4 = (float4*)(out + (size_t)p * kL);
#pragma unroll
  for (int i = 0; i < kL; i += 2) {
    const int l = (lstart + i) & (kL - 1);
    op4[l >> 1] = make_float4(acc[i].x, acc[i].y, acc[i + 1].x, acc[i + 1].y);
  }
}

extern "C" void kernel_launch(void* const* d_in, const int* in_sizes, int n_in,
                              void* d_out, int out_size, void* d_ws, size_t ws_size,
                              hipStream_t stream) {
  const float* x = (const float*)d_in[0];

  Scales sc;
  const float b = expf(logf(256.0f) / 15.0f);
  for (int l = 0; l < kL; ++l)
    sc.s[l] = floorf(16.0f * powf(b, (float)l));

  const size_t ws_needed = (size_t)kL * kN * sizeof(f32x2);  // 64 MiB
  if (ws_size >= ws_needed) {
    hipLaunchKernelGGL(hashenc_gather, dim3(8 * 2 * kChunks), dim3(256), 0,
                       stream, x, (const f32x2*)d_in[1], (f32x2*)d_ws, sc);
    hipLaunchKernelGGL(hashenc_transpose, dim3(kN / 256), dim3(256), 0,
                       stream, (const f32x2*)d_ws, (f32x4*)d_out);
  } else {
    hipLaunchKernelGGL(hashenc_direct, dim3(kN / 256), dim3(256), 0, stream,
                       x, (const float2*)d_in[1], (float2*)d_out, sc);
  }
}

// Round 5
// 228.626 us; speedup vs baseline: 3.0566x; 1.8177x over previous
//
#include <hip/hip_runtime.h>
#include <cmath>
#include <cstdint>

namespace {
constexpr int      kL  = 16;
constexpr uint32_t kT  = 1u << 19;       // 524288 entries per level
constexpr int      kN  = 524288;         // points
constexpr int      kChunks = kN / 256;   // 2048 point-chunks
constexpr uint32_t PI2 = 2654435761u;
constexpr uint32_t PI3 = 805459861u;

typedef float f32x2 __attribute__((ext_vector_type(2)));
typedef float f32x4 __attribute__((ext_vector_type(4)));

struct Scales { float s[kL]; };
} // namespace

// ---------------- Phase 1: gather, level-major output ----------------
// Hard level<->XCD affinity: b&7 -> XCD c; XCD c does level c for all points,
// then level 15-c. One 4-MB table resident per XCD L2 at a time.
// x loads non-temporal (don't evict the table); ws stores non-temporal
// (level-major, 512 B/wave contiguous full lines).
// x-corner pairing: PIS[0]==1 => for even c0 the two x-corners are the
// aligned table pair {i0&~1, i0|1} -> one f32x4 load replaces two f32x2
// gathers (halves requests for ~50% of lanes).
__global__ __launch_bounds__(256) void hashenc_gather(
    const float* __restrict__ x,       // (N, 3)
    const f32x2* __restrict__ tab,     // (L, T)
    const f32x4* __restrict__ tab4,    // same memory as (L, T/2) pairs
    f32x2* __restrict__ ws,            // (L, N)
    Scales sc)
{
  const int c = blockIdx.x & 7;
  const int j = blockIdx.x >> 3;
  const int l = (j < kChunks) ? c : (15 - c);
  const int p = (j & (kChunks - 1)) * 256 + threadIdx.x;

  const float s  = sc.s[l];
  const float p0 = __builtin_nontemporal_load(x + 3 * p + 0) * s;
  const float p1 = __builtin_nontemporal_load(x + 3 * p + 1) * s;
  const float p2 = __builtin_nontemporal_load(x + 3 * p + 2) * s;
  const float f0 = floorf(p0), f1 = floorf(p1), f2 = floorf(p2);
  const float r0 = p0 - f0, r1 = p1 - f1, r2 = p2 - f2;

  const uint32_t h0  = (uint32_t)(int)f0;              // PI1 == 1
  const uint32_t hy0 = (uint32_t)(int)f1 * PI2, hy1 = hy0 + PI2;
  const uint32_t hz0 = (uint32_t)(int)f2 * PI3, hz1 = hz0 + PI3;
  const bool even = (h0 & 1u) == 0u;

  const float wx0 = 1.0f - r0, wx1 = r0;
  const float wy[2] = {1.0f - r1, r1};
  const float wz[2] = {1.0f - r2, r2};

  const f32x2* tl  = tab  + (size_t)l * kT;
  const f32x4* tl4 = tab4 + (size_t)l * (kT / 2);
  float a0 = 0.0f, a1 = 0.0f;

#pragma unroll
  for (int oy = 0; oy < 2; ++oy)
#pragma unroll
    for (int oz = 0; oz < 2; ++oz) {
      const uint32_t hyz = (oy ? hy1 : hy0) ^ (oz ? hz1 : hz0);
      const uint32_t i0  = (h0 ^ hyz) & (kT - 1u);
      float g0x, g0y, g1x, g1y;
      if (even) {
        // c0 even: corner(ox=1) index = i0^1 -> aligned pair at i0>>1.
        const f32x4 q = tl4[i0 >> 1];
        const bool lo = (i0 & 1u) == 0u;
        g0x = lo ? q.x : q.z;  g0y = lo ? q.y : q.w;
        g1x = lo ? q.z : q.x;  g1y = lo ? q.w : q.y;
      } else {
        const uint32_t i1 = ((h0 + 1u) ^ hyz) & (kT - 1u);
        const f32x2 g0 = tl[i0];
        const f32x2 g1 = tl[i1];
        g0x = g0.x; g0y = g0.y; g1x = g1.x; g1y = g1.y;
      }
      const float wyz = wy[oy] * wz[oz];
      a0 += wyz * (wx0 * g0x + wx1 * g1x);
      a1 += wyz * (wx0 * g0y + wx1 * g1y);
    }

  f32x2 r; r.x = a0; r.y = a1;
  __builtin_nontemporal_store(r, ws + (size_t)l * kN + p);
}

// ---------------- Phase 2: transpose (L,N,2) -> (N,L,2) ----------------
// One 16-B output chunk per thread. Per wave: 16 source lines, each fully
// consumed; stores lane-contiguous full lines. No LDS, no barrier.
__global__ __launch_bounds__(256) void hashenc_transpose(
    const f32x2* __restrict__ ws,      // (L, N)
    f32x4* __restrict__ out)           // (N*L/2) chunks
{
  const int g  = blockIdx.x * 256 + threadIdx.x;   // chunk id in [0, N*8)
  const int pt = g >> 3;                           // point
  const int pr = g & 7;                            // level pair
  const f32x2 e = __builtin_nontemporal_load(ws + (size_t)(2 * pr)     * kN + pt);
  const f32x2 o = __builtin_nontemporal_load(ws + (size_t)(2 * pr + 1) * kN + pt);
  f32x4 v; v.x = e.x; v.y = e.y; v.z = o.x; v.w = o.y;
  __builtin_nontemporal_store(v, out + g);
}

// ---------------- Fallback: direct (N,L) writes (R2 kernel) ----------------
__global__ __launch_bounds__(256) void hashenc_direct(
    const float* __restrict__ x, const float2* __restrict__ tab,
    float2* __restrict__ out, Scales sc)
{
  const int p = blockIdx.x * 256 + threadIdx.x;
  const int lstart = (blockIdx.x & 7) * 2;
  const float x0 = x[3 * p + 0], x1 = x[3 * p + 1], x2 = x[3 * p + 2];
  float2 acc[kL];
#pragma unroll
  for (int i = 0; i < kL; ++i) {
    const int l = (lstart + i) & (kL - 1);
    const float s = sc.s[l];
    const float p0 = x0 * s, p1 = x1 * s, p2 = x2 * s;
    const float f0 = floorf(p0), f1 = floorf(p1), f2 = floorf(p2);
    const float r0 = p0 - f0, r1 = p1 - f1, r2 = p2 - f2;
    uint32_t hx[2], hy[2], hz[2];
    hx[0] = (uint32_t)(int)f0;       hx[1] = hx[0] + 1u;
    hy[0] = (uint32_t)(int)f1 * PI2; hy[1] = hy[0] + PI2;
    hz[0] = (uint32_t)(int)f2 * PI3; hz[1] = hz[0] + PI3;
    float wxa[2] = {1.0f - r0, r0}, wya[2] = {1.0f - r1, r1}, wza[2] = {1.0f - r2, r2};
    const float2* tl = tab + (size_t)l * kT;
    float a0 = 0.0f, a1 = 0.0f;
#pragma unroll
    for (int ox = 0; ox < 2; ++ox)
#pragma unroll
      for (int oy = 0; oy < 2; ++oy)
#pragma unroll
        for (int oz = 0; oz < 2; ++oz) {
          const uint32_t idx = (hx[ox] ^ hy[oy] ^ hz[oz]) & (kT - 1u);
          const float2 g = tl[idx];
          const float  w = (wxa[ox] * wya[oy]) * wza[oz];
          a0 += w * g.x; a1 += w * g.y;
        }
    acc[i] = make_float2(a0, a1);
  }
  float4* op4 = (float4*)(out + (size_t)p * kL);
#pragma unroll
  for (int i = 0; i < kL; i += 2) {
    const int l = (lstart + i) & (kL - 1);
    op4[l >> 1] = make_float4(acc[i].x, acc[i].y, acc[i + 1].x, acc[i + 1].y);
  }
}

extern "C" void kernel_launch(void* const* d_in, const int* in_sizes, int n_in,
                              void* d_out, int out_size, void* d_ws, size_t ws_size,
                              hipStream_t stream) {
  const float* x = (const float*)d_in[0];

  Scales sc;
  const float b = expf(logf(256.0f) / 15.0f);
  for (int l = 0; l < kL; ++l)
    sc.s[l] = floorf(16.0f * powf(b, (float)l));

  const size_t ws_needed = (size_t)kL * kN * sizeof(f32x2);  // 64 MiB
  if (ws_size >= ws_needed) {
    hipLaunchKernelGGL(hashenc_gather, dim3(8 * 2 * kChunks), dim3(256), 0,
                       stream, x, (const f32x2*)d_in[1], (const f32x4*)d_in[1],
                       (f32x2*)d_ws, sc);
    hipLaunchKernelGGL(hashenc_transpose, dim3(kN * 8 / 256), dim3(256), 0,
                       stream, (const f32x2*)d_ws, (f32x4*)d_out);
  } else {
    hipLaunchKernelGGL(hashenc_direct, dim3(kN / 256), dim3(256), 0, stream,
                       x, (const float2*)d_in[1], (float2*)d_out, sc);
  }
}